// Round 1
// baseline (950.891 us; speedup 1.0000x reference)
//
#include <hip/hip_runtime.h>

#define Bg   128
#define NPG  512
#define EPGc 8192
#define Etot (Bg*EPGc)
#define DOUTc 10
#define K1c  410
#define K2c  328
#define N0c  (Bg*NPG)
#define N1c  (Bg*K1c)
#define N2c  (Bg*K2c)
#define EPSc 1e-5f

// ---------------- utility fills ----------------
static __global__ void k_fill_i32(int* p, int v, int n) {
  int i = blockIdx.x * 256 + threadIdx.x;
  if (i < n) p[i] = v;
}

// count in-degree (alive edges only; dst<0 = masked)
static __global__ void k_cnt(const int* __restrict__ dst, int* __restrict__ cnt, int e) {
  int i = blockIdx.x * 256 + threadIdx.x;
  if (i < e) { int d = dst[i]; if (d >= 0) atomicAdd(&cnt[d], 1); }
}

static __global__ void k_dinv(const int* __restrict__ cnt, float* __restrict__ dinv, int n) {
  int i = blockIdx.x * 256 + threadIdx.x;
  if (i < n) dinv[i] = 1.0f / sqrtf(1.0f + (float)cnt[i]);
}

// per-graph exclusive scan of counts -> row_ptr (nper+1 entries per graph)
static __global__ __launch_bounds__(512) void k_rowscan(const int* __restrict__ cnt,
                                                        int* __restrict__ rp, int nper) {
  __shared__ int sbuf[512];
  int g = blockIdx.x, tid = threadIdx.x;
  int v = (tid < nper) ? cnt[g * nper + tid] : 0;
  sbuf[tid] = v;
  __syncthreads();
  for (int off = 1; off < 512; off <<= 1) {
    int t = (tid >= off) ? sbuf[tid - off] : 0;
    __syncthreads();
    sbuf[tid] += t;
    __syncthreads();
  }
  if (tid < nper) rp[g * (nper + 1) + tid] = sbuf[tid] - v;   // exclusive
  if (tid == 511) rp[g * (nper + 1) + nper] = sbuf[511];      // total
}

// scatter edges into CSR slots (per-graph slot range [g*EPG,(g+1)*EPG))
static __global__ void k_fill_csr(const int* __restrict__ src, const int* __restrict__ dst,
                                  const float* __restrict__ dinv, const int* __restrict__ rp,
                                  int* __restrict__ fcnt, int* __restrict__ col,
                                  float* __restrict__ cval, int nper, int e) {
  int i = blockIdx.x * 256 + threadIdx.x;
  if (i >= e) return;
  int d = dst[i];
  if (d < 0) return;
  int s = src[i];
  int g = i >> 13;                       // EPG = 8192 edges per graph slot
  int local = d - g * nper;
  int pos = g * EPGc + rp[g * (nper + 1) + local] + atomicAdd(&fcnt[d], 1);
  col[pos] = s;
  cval[pos] = dinv[s] * dinv[d];
}

// ---------------- GEMM: Y[M x 128] = X[M x 128] @ W[128 x 128] ----------------
static __global__ __launch_bounds__(256) void k_gemm(const float* __restrict__ X,
                                                     const float* __restrict__ W,
                                                     float* __restrict__ Y, int M) {
  __shared__ float ws[128 * 128];      // 64 KB
  __shared__ float xsT[128][64];       // 32 KB, k-major
  int tid = threadIdx.x;
  for (int i = tid; i < 4096; i += 256) ((float4*)ws)[i] = ((const float4*)W)[i];
  int row0 = blockIdx.x * 64;
  for (int i = tid; i < 2048; i += 256) {
    int r = i >> 5, kq = i & 31;
    float4 v = ((const float4*)X)[(size_t)(row0 + r) * 32 + kq];
    int k = kq << 2;
    xsT[k][r] = v.x; xsT[k + 1][r] = v.y; xsT[k + 2][r] = v.z; xsT[k + 3][r] = v.w;
  }
  __syncthreads();
  int tx = tid & 15, ty = tid >> 4;    // thread tile: 4 rows x 8 cols
  float acc[4][8];
#pragma unroll
  for (int i = 0; i < 4; ++i)
#pragma unroll
    for (int j = 0; j < 8; ++j) acc[i][j] = 0.f;
#pragma unroll 4
  for (int k = 0; k < 128; ++k) {
    float4 xv = *(const float4*)&xsT[k][ty * 4];
    float4 wa = *(const float4*)&ws[k * 128 + tx * 8];
    float4 wb = *(const float4*)&ws[k * 128 + tx * 8 + 4];
    float xr[4] = {xv.x, xv.y, xv.z, xv.w};
    float wr[8] = {wa.x, wa.y, wa.z, wa.w, wb.x, wb.y, wb.z, wb.w};
#pragma unroll
    for (int i = 0; i < 4; ++i)
#pragma unroll
      for (int j = 0; j < 8; ++j) acc[i][j] += xr[i] * wr[j];
  }
#pragma unroll
  for (int i = 0; i < 4; ++i) {
    int row = row0 + ty * 4 + i;
    float4 o1 = make_float4(acc[i][0], acc[i][1], acc[i][2], acc[i][3]);
    float4 o2 = make_float4(acc[i][4], acc[i][5], acc[i][6], acc[i][7]);
    ((float4*)Y)[(size_t)row * 32 + tx * 2] = o1;
    ((float4*)Y)[(size_t)row * 32 + tx * 2 + 1] = o2;
  }
}

// GCN aggregation via CSR: h1[j] = h0[j]*dinv[j]^2 + bias + sum_e cval*h0[col]
static __global__ __launch_bounds__(128) void k_agg(const float* __restrict__ h0,
                                                    const float* __restrict__ dinv,
                                                    const float* __restrict__ bias,
                                                    const int* __restrict__ rp,
                                                    const int* __restrict__ col,
                                                    const float* __restrict__ cval,
                                                    float* __restrict__ h1, int nper) {
  int j = blockIdx.x, f = threadIdx.x;
  int g = j / nper, li = j - g * nper;
  int start = g * EPGc + rp[g * (nper + 1) + li];
  int end   = g * EPGc + rp[g * (nper + 1) + li + 1];
  float di = dinv[j];
  float acc = h0[(size_t)j * 128 + f] * di * di + bias[f];
  for (int e = start; e < end; ++e) {
    int s = col[e];
    float c = cval[e];
    acc += h0[(size_t)s * 128 + f] * c;
  }
  h1[(size_t)j * 128 + f] = acc;
}

// spre[i] = dot(h[i,:], w)   (one wave64 per node)
static __global__ __launch_bounds__(256) void k_gemv(const float* __restrict__ h,
                                                     const float* __restrict__ w,
                                                     float* __restrict__ out, int n) {
  int node = blockIdx.x * 4 + (threadIdx.x >> 6);
  int lane = threadIdx.x & 63;
  if (node >= n) return;
  float a = h[(size_t)node * 128 + lane] * w[lane] +
            h[(size_t)node * 128 + 64 + lane] * w[64 + lane];
  for (int off = 32; off > 0; off >>= 1) a += __shfl_xor(a, off, 64);
  if (lane == 0) out[node] = a;
}

// s[j] = spre[j]*dinv^2 + b + sum_e cval*spre[col]
static __global__ void k_score(const float* __restrict__ spre, const float* __restrict__ dinv,
                               const float* __restrict__ bptr, const int* __restrict__ rp,
                               const int* __restrict__ col, const float* __restrict__ cval,
                               float* __restrict__ s, int nper, int n) {
  int j = blockIdx.x * 256 + threadIdx.x;
  if (j >= n) return;
  int g = j / nper, li = j - g * nper;
  int start = g * EPGc + rp[g * (nper + 1) + li];
  int end   = g * EPGc + rp[g * (nper + 1) + li + 1];
  float di = dinv[j];
  float acc = spre[j] * di * di + bptr[0];
  for (int e = start; e < end; ++e) acc += spre[col[e]] * cval[e];
  s[j] = acc;
}

// per-graph top-K by bitonic sort of (score, idx) in LDS; only the SET matters downstream
template <int NPER, int K>
static __global__ __launch_bounds__(256) void k_topk(const float* __restrict__ s,
                                                     int* __restrict__ perm) {
  __shared__ float sc[512];
  __shared__ int   idx[512];
  int g = blockIdx.x, tid = threadIdx.x;
  for (int i = tid; i < 512; i += 256) {
    if (i < NPER) { sc[i] = s[g * NPER + i]; idx[i] = i; }
    else          { sc[i] = -3.402823466e38f; idx[i] = 0; }
  }
  __syncthreads();
  for (int kk = 2; kk <= 512; kk <<= 1) {
    for (int j = kk >> 1; j > 0; j >>= 1) {
      for (int base = 0; base < 512; base += 256) {
        int i = base + tid;
        int p = i ^ j;
        if (p > i) {
          bool up = ((i & kk) == 0);          // descending overall
          float si = sc[i], sp = sc[p];
          if (up ? (si < sp) : (si > sp)) {
            sc[i] = sp; sc[p] = si;
            int t = idx[i]; idx[i] = idx[p]; idx[p] = t;
          }
        }
      }
      __syncthreads();
    }
  }
  for (int r = tid; r < K; r += 256) perm[g * K + r] = g * NPER + idx[r];
}

static __global__ void k_remap_scatter(const int* __restrict__ perm, int* __restrict__ remap, int n) {
  int j = blockIdx.x * 256 + threadIdx.x;
  if (j < n) remap[perm[j]] = j;
}

static __global__ void k_edge_remap(const int* __restrict__ src, const int* __restrict__ dst,
                                    const int* __restrict__ remap, int* __restrict__ es,
                                    int* __restrict__ ed, int e) {
  int i = blockIdx.x * 256 + threadIdx.x;
  if (i >= e) return;
  int s2 = remap[src[i]];
  int d2 = remap[dst[i]];
  bool alive = (s2 >= 0) && (d2 >= 0);
  es[i] = alive ? s2 : -1;
  ed[i] = alive ? d2 : -1;
}

// xp[j] = relu(bn( h[perm[j]] * tanh(s[perm[j]]) ))
static __global__ __launch_bounds__(128) void k_pool_bn(const float* __restrict__ h,
                                                        const float* __restrict__ s,
                                                        const int* __restrict__ perm,
                                                        const float* __restrict__ gg,
                                                        const float* __restrict__ bb,
                                                        const float* __restrict__ mm,
                                                        const float* __restrict__ vv,
                                                        float* __restrict__ xp) {
  int j = blockIdx.x, f = threadIdx.x;
  int old = perm[j];
  float t = tanhf(s[old]);
  float val = h[(size_t)old * 128 + f] * t;
  float o = gg[f] * (val - mm[f]) / sqrtf(vv[f] + EPSc) + bb[f];
  xp[(size_t)j * 128 + f] = fmaxf(o, 0.0f);
}

static __global__ __launch_bounds__(128) void k_gsum(const float* __restrict__ xp,
                                                     float* __restrict__ pooled, int nper) {
  int g = blockIdx.x, f = threadIdx.x;
  float acc = 0.f;
  const float* p = xp + (size_t)g * nper * 128 + f;
  for (int i = 0; i < nper; ++i) acc += p[(size_t)i * 128];
  pooled[g * 128 + f] = acc;
}

static __global__ void k_final(const float* __restrict__ pooled,
                               const float* __restrict__ w0, const float* __restrict__ b0,
                               const float* __restrict__ w1, const float* __restrict__ b1,
                               const float* __restrict__ w2, const float* __restrict__ b2,
                               float* __restrict__ out) {
  int t = blockIdx.x * 256 + threadIdx.x;
  if (t >= Bg * DOUTc) return;
  int g = t / DOUTc, o = t - g * DOUTc;
  const float* p0 = pooled + g * 128;
  const float* p1 = pooled + Bg * 128 + g * 128;
  const float* p2 = pooled + 2 * Bg * 128 + g * 128;
  float acc = b0[o] + b1[o] + b2[o];
  for (int k = 0; k < 128; ++k)
    acc += p0[k] * w0[o * 128 + k] + p1[k] * w1[o * 128 + k] + p2[k] * w2[o * 128 + k];
  out[t] = acc;
}

extern "C" void kernel_launch(void* const* d_in, const int* in_sizes, int n_in,
                              void* d_out, int out_size, void* d_ws, size_t ws_size,
                              hipStream_t stream) {
  (void)in_sizes; (void)n_in; (void)out_size; (void)ws_size;
  const float* x    = (const float*)d_in[0];
  const int*   ei   = (const int*)d_in[1];
  const int*   src0 = ei;
  const int*   dst0 = ei + Etot;
  const float* c1W = (const float*)d_in[2];  const float* c1b = (const float*)d_in[3];
  const float* c2W = (const float*)d_in[4];  const float* c2b = (const float*)d_in[5];
  const float* s1W = (const float*)d_in[6];  const float* s1b = (const float*)d_in[7];
  const float* s2W = (const float*)d_in[8];  const float* s2b = (const float*)d_in[9];
  const float* bn1g = (const float*)d_in[10]; const float* bn1b = (const float*)d_in[11];
  const float* bn1m = (const float*)d_in[12]; const float* bn1v = (const float*)d_in[13];
  const float* bn2g = (const float*)d_in[14]; const float* bn2b = (const float*)d_in[15];
  const float* bn2m = (const float*)d_in[16]; const float* bn2v = (const float*)d_in[17];
  const float* l0W = (const float*)d_in[18]; const float* l0b = (const float*)d_in[19];
  const float* l1W = (const float*)d_in[20]; const float* l1b = (const float*)d_in[21];
  const float* l2W = (const float*)d_in[22]; const float* l2b = (const float*)d_in[23];
  float* out = (float*)d_out;

  char* p = (char*)d_ws;
  auto alloc = [&](size_t bytes) { char* q = p; p += (bytes + 255) & ~(size_t)255; return q; };
  float* h0    = (float*)alloc((size_t)N0c * 128 * 4);   // layer1 reuses as g1
  float* h1    = (float*)alloc((size_t)N0c * 128 * 4);   // layer1 reuses as h2
  float* xp1   = (float*)alloc((size_t)N1c * 128 * 4);
  float* xp2   = (float*)alloc((size_t)N2c * 128 * 4);
  int*   cnt   = (int*)alloc((size_t)N0c * 4);
  int*   fcnt  = (int*)alloc((size_t)N0c * 4);
  float* dinv  = (float*)alloc((size_t)N0c * 4);
  int*   rp    = (int*)alloc((size_t)Bg * (NPG + 1) * 4);
  int*   col   = (int*)alloc((size_t)Etot * 4);
  float* cval  = (float*)alloc((size_t)Etot * 4);
  float* spre  = (float*)alloc((size_t)N0c * 4);
  float* sv    = (float*)alloc((size_t)N0c * 4);
  int*   perm  = (int*)alloc((size_t)N1c * 4);
  int*   remap = (int*)alloc((size_t)N0c * 4);
  int*   es    = (int*)alloc((size_t)Etot * 4);
  int*   ed    = (int*)alloc((size_t)Etot * 4);
  float* pooled= (float*)alloc((size_t)3 * Bg * 128 * 4);

  dim3 b256(256), b128(128), b512(512);
  int gE = (Etot + 255) / 256;

  // ---------------- layer 0 ----------------
  k_fill_i32<<<(N0c + 255) / 256, b256, 0, stream>>>(cnt, 0, N0c);
  k_cnt<<<gE, b256, 0, stream>>>(dst0, cnt, Etot);
  k_dinv<<<(N0c + 255) / 256, b256, 0, stream>>>(cnt, dinv, N0c);
  k_rowscan<<<Bg, b512, 0, stream>>>(cnt, rp, NPG);
  k_fill_i32<<<(N0c + 255) / 256, b256, 0, stream>>>(fcnt, 0, N0c);
  k_fill_csr<<<gE, b256, 0, stream>>>(src0, dst0, dinv, rp, fcnt, col, cval, NPG, Etot);
  k_gemm<<<N0c / 64, b256, 0, stream>>>(x, c1W, h0, N0c);
  k_agg<<<N0c, b128, 0, stream>>>(h0, dinv, c1b, rp, col, cval, h1, NPG);
  k_gemv<<<(N0c + 3) / 4, b256, 0, stream>>>(h1, s1W, spre, N0c);
  k_score<<<(N0c + 255) / 256, b256, 0, stream>>>(spre, dinv, s1b, rp, col, cval, sv, NPG, N0c);
  k_topk<NPG, K1c><<<Bg, b256, 0, stream>>>(sv, perm);
  k_fill_i32<<<(N0c + 255) / 256, b256, 0, stream>>>(remap, -1, N0c);
  k_remap_scatter<<<(N1c + 255) / 256, b256, 0, stream>>>(perm, remap, N1c);
  k_edge_remap<<<gE, b256, 0, stream>>>(src0, dst0, remap, es, ed, Etot);
  k_pool_bn<<<N1c, b128, 0, stream>>>(h1, sv, perm, bn1g, bn1b, bn1m, bn1v, xp1);

  // ---------------- layer 1 ----------------
  k_fill_i32<<<(N1c + 255) / 256, b256, 0, stream>>>(cnt, 0, N1c);
  k_cnt<<<gE, b256, 0, stream>>>(ed, cnt, Etot);
  k_dinv<<<(N1c + 255) / 256, b256, 0, stream>>>(cnt, dinv, N1c);
  k_rowscan<<<Bg, b512, 0, stream>>>(cnt, rp, K1c);
  k_fill_i32<<<(N1c + 255) / 256, b256, 0, stream>>>(fcnt, 0, N1c);
  k_fill_csr<<<gE, b256, 0, stream>>>(es, ed, dinv, rp, fcnt, col, cval, K1c, Etot);
  float* g1 = h0;   // h0 dead after layer-0 agg
  float* h2 = h1;   // h1 dead after pool_bn
  k_gemm<<<N1c / 64, b256, 0, stream>>>(xp1, c2W, g1, N1c);
  k_agg<<<N1c, b128, 0, stream>>>(g1, dinv, c2b, rp, col, cval, h2, K1c);
  k_gemv<<<(N1c + 3) / 4, b256, 0, stream>>>(h2, s2W, spre, N1c);
  k_score<<<(N1c + 255) / 256, b256, 0, stream>>>(spre, dinv, s2b, rp, col, cval, sv, K1c, N1c);
  k_topk<K1c, K2c><<<Bg, b256, 0, stream>>>(sv, perm);
  k_pool_bn<<<N2c, b128, 0, stream>>>(h2, sv, perm, bn2g, bn2b, bn2m, bn2v, xp2);

  // ---------------- readout ----------------
  k_gsum<<<Bg, b128, 0, stream>>>(x, pooled, NPG);
  k_gsum<<<Bg, b128, 0, stream>>>(xp1, pooled + Bg * 128, K1c);
  k_gsum<<<Bg, b128, 0, stream>>>(xp2, pooled + 2 * Bg * 128, K2c);
  k_final<<<(Bg * DOUTc + 255) / 256, b256, 0, stream>>>(pooled, l0W, l0b, l1W, l1b, l2W, l2b, out);
}

// Round 2
// 681.155 us; speedup vs baseline: 1.3960x; 1.3960x over previous
//
#include <hip/hip_runtime.h>

#define Bg   128
#define NPG  512
#define EPGc 8192
#define Etot (Bg*EPGc)
#define DOUTc 10
#define K1c  410
#define K2c  328
#define N0c  (Bg*NPG)
#define N1c  (Bg*K1c)
#define N2c  (Bg*K2c)
#define EPSc 1e-5f

// ---------------- utility fills ----------------
static __global__ void k_fill_i32(int* p, int v, int n) {
  int i = blockIdx.x * 256 + threadIdx.x;
  if (i < n) p[i] = v;
}

static __global__ void k_fill_f32(float* p, float v, int n) {
  int i = blockIdx.x * 256 + threadIdx.x;
  if (i < n) p[i] = v;
}

// count in-degree (alive edges only; dst<0 = masked)
static __global__ void k_cnt(const int* __restrict__ dst, int* __restrict__ cnt, int e) {
  int i = blockIdx.x * 256 + threadIdx.x;
  if (i < e) { int d = dst[i]; if (d >= 0) atomicAdd(&cnt[d], 1); }
}

static __global__ void k_dinv(const int* __restrict__ cnt, float* __restrict__ dinv, int n) {
  int i = blockIdx.x * 256 + threadIdx.x;
  if (i < n) dinv[i] = 1.0f / sqrtf(1.0f + (float)cnt[i]);
}

// per-graph exclusive scan of counts -> row_ptr (nper+1 entries per graph)
static __global__ __launch_bounds__(512) void k_rowscan(const int* __restrict__ cnt,
                                                        int* __restrict__ rp, int nper) {
  __shared__ int sbuf[512];
  int g = blockIdx.x, tid = threadIdx.x;
  int v = (tid < nper) ? cnt[g * nper + tid] : 0;
  sbuf[tid] = v;
  __syncthreads();
  for (int off = 1; off < 512; off <<= 1) {
    int t = (tid >= off) ? sbuf[tid - off] : 0;
    __syncthreads();
    sbuf[tid] += t;
    __syncthreads();
  }
  if (tid < nper) rp[g * (nper + 1) + tid] = sbuf[tid] - v;   // exclusive
  if (tid == 511) rp[g * (nper + 1) + nper] = sbuf[511];      // total
}

// scatter edges into CSR slots (per-graph slot range [g*EPG,(g+1)*EPG))
static __global__ void k_fill_csr(const int* __restrict__ src, const int* __restrict__ dst,
                                  const float* __restrict__ dinv, const int* __restrict__ rp,
                                  int* __restrict__ fcnt, int* __restrict__ col,
                                  float* __restrict__ cval, int nper, int e) {
  int i = blockIdx.x * 256 + threadIdx.x;
  if (i >= e) return;
  int d = dst[i];
  if (d < 0) return;
  int s = src[i];
  int g = i >> 13;                       // EPG = 8192 edges per graph slot
  int local = d - g * nper;
  int pos = g * EPGc + rp[g * (nper + 1) + local] + atomicAdd(&fcnt[d], 1);
  col[pos] = s;
  cval[pos] = dinv[s] * dinv[d];
}

// ---------------- GEMM: Y[M x 128] = X[M x 128] @ W[128 x 128] ----------------
static __global__ __launch_bounds__(256) void k_gemm(const float* __restrict__ X,
                                                     const float* __restrict__ W,
                                                     float* __restrict__ Y, int M) {
  __shared__ float ws[128 * 128];      // 64 KB
  __shared__ float xsT[128][64];       // 32 KB, k-major
  int tid = threadIdx.x;
  for (int i = tid; i < 4096; i += 256) ((float4*)ws)[i] = ((const float4*)W)[i];
  int row0 = blockIdx.x * 64;
  for (int i = tid; i < 2048; i += 256) {
    int r = i >> 5, kq = i & 31;
    float4 v = ((const float4*)X)[(size_t)(row0 + r) * 32 + kq];
    int k = kq << 2;
    xsT[k][r] = v.x; xsT[k + 1][r] = v.y; xsT[k + 2][r] = v.z; xsT[k + 3][r] = v.w;
  }
  __syncthreads();
  int tx = tid & 15, ty = tid >> 4;    // thread tile: 4 rows x 8 cols
  float acc[4][8];
#pragma unroll
  for (int i = 0; i < 4; ++i)
#pragma unroll
    for (int j = 0; j < 8; ++j) acc[i][j] = 0.f;
#pragma unroll 4
  for (int k = 0; k < 128; ++k) {
    float4 xv = *(const float4*)&xsT[k][ty * 4];
    float4 wa = *(const float4*)&ws[k * 128 + tx * 8];
    float4 wb = *(const float4*)&ws[k * 128 + tx * 8 + 4];
    float xr[4] = {xv.x, xv.y, xv.z, xv.w};
    float wr[8] = {wa.x, wa.y, wa.z, wa.w, wb.x, wb.y, wb.z, wb.w};
#pragma unroll
    for (int i = 0; i < 4; ++i)
#pragma unroll
      for (int j = 0; j < 8; ++j) acc[i][j] += xr[i] * wr[j];
  }
#pragma unroll
  for (int i = 0; i < 4; ++i) {
    int row = row0 + ty * 4 + i;
    float4 o1 = make_float4(acc[i][0], acc[i][1], acc[i][2], acc[i][3]);
    float4 o2 = make_float4(acc[i][4], acc[i][5], acc[i][6], acc[i][7]);
    ((float4*)Y)[(size_t)row * 32 + tx * 2] = o1;
    ((float4*)Y)[(size_t)row * 32 + tx * 2 + 1] = o2;
  }
}

// GCN aggregation via CSR: h1[j] = h0[j]*dinv[j]^2 + bias + sum_e cval*h0[col]
static __global__ __launch_bounds__(128) void k_agg(const float* __restrict__ h0,
                                                    const float* __restrict__ dinv,
                                                    const float* __restrict__ bias,
                                                    const int* __restrict__ rp,
                                                    const int* __restrict__ col,
                                                    const float* __restrict__ cval,
                                                    float* __restrict__ h1, int nper) {
  int j = blockIdx.x, f = threadIdx.x;
  int g = j / nper, li = j - g * nper;
  int start = g * EPGc + rp[g * (nper + 1) + li];
  int end   = g * EPGc + rp[g * (nper + 1) + li + 1];
  float di = dinv[j];
  float acc = h0[(size_t)j * 128 + f] * di * di + bias[f];
  for (int e = start; e < end; ++e) {
    int s = col[e];
    float c = cval[e];
    acc += h0[(size_t)s * 128 + f] * c;
  }
  h1[(size_t)j * 128 + f] = acc;
}

// spre[i] = dot(h[i,:], w)   (one wave64 per node)
static __global__ __launch_bounds__(256) void k_gemv(const float* __restrict__ h,
                                                     const float* __restrict__ w,
                                                     float* __restrict__ out, int n) {
  int node = blockIdx.x * 4 + (threadIdx.x >> 6);
  int lane = threadIdx.x & 63;
  if (node >= n) return;
  float a = h[(size_t)node * 128 + lane] * w[lane] +
            h[(size_t)node * 128 + 64 + lane] * w[64 + lane];
  for (int off = 32; off > 0; off >>= 1) a += __shfl_xor(a, off, 64);
  if (lane == 0) out[node] = a;
}

// s[j] = spre[j]*dinv^2 + b + sum_e cval*spre[col]
static __global__ void k_score(const float* __restrict__ spre, const float* __restrict__ dinv,
                               const float* __restrict__ bptr, const int* __restrict__ rp,
                               const int* __restrict__ col, const float* __restrict__ cval,
                               float* __restrict__ s, int nper, int n) {
  int j = blockIdx.x * 256 + threadIdx.x;
  if (j >= n) return;
  int g = j / nper, li = j - g * nper;
  int start = g * EPGc + rp[g * (nper + 1) + li];
  int end   = g * EPGc + rp[g * (nper + 1) + li + 1];
  float di = dinv[j];
  float acc = spre[j] * di * di + bptr[0];
  for (int e = start; e < end; ++e) acc += spre[col[e]] * cval[e];
  s[j] = acc;
}

// per-graph top-K by bitonic sort of (score, idx) in LDS; only the SET matters downstream
template <int NPER, int K>
static __global__ __launch_bounds__(256) void k_topk(const float* __restrict__ s,
                                                     int* __restrict__ perm) {
  __shared__ float sc[512];
  __shared__ int   idx[512];
  int g = blockIdx.x, tid = threadIdx.x;
  for (int i = tid; i < 512; i += 256) {
    if (i < NPER) { sc[i] = s[g * NPER + i]; idx[i] = i; }
    else          { sc[i] = -3.402823466e38f; idx[i] = 0; }
  }
  __syncthreads();
  for (int kk = 2; kk <= 512; kk <<= 1) {
    for (int j = kk >> 1; j > 0; j >>= 1) {
      for (int base = 0; base < 512; base += 256) {
        int i = base + tid;
        int p = i ^ j;
        if (p > i) {
          bool up = ((i & kk) == 0);          // descending overall
          float si = sc[i], sp = sc[p];
          if (up ? (si < sp) : (si > sp)) {
            sc[i] = sp; sc[p] = si;
            int t = idx[i]; idx[i] = idx[p]; idx[p] = t;
          }
        }
      }
      __syncthreads();
    }
  }
  for (int r = tid; r < K; r += 256) perm[g * K + r] = g * NPER + idx[r];
}

static __global__ void k_remap_scatter(const int* __restrict__ perm, int* __restrict__ remap, int n) {
  int j = blockIdx.x * 256 + threadIdx.x;
  if (j < n) remap[perm[j]] = j;
}

static __global__ void k_edge_remap(const int* __restrict__ src, const int* __restrict__ dst,
                                    const int* __restrict__ remap, int* __restrict__ es,
                                    int* __restrict__ ed, int e) {
  int i = blockIdx.x * 256 + threadIdx.x;
  if (i >= e) return;
  int s2 = remap[src[i]];
  int d2 = remap[dst[i]];
  bool alive = (s2 >= 0) && (d2 >= 0);
  es[i] = alive ? s2 : -1;
  ed[i] = alive ? d2 : -1;
}

// xp[j] = relu(bn( h[perm[j]] * tanh(s[perm[j]]) ))
static __global__ __launch_bounds__(128) void k_pool_bn(const float* __restrict__ h,
                                                        const float* __restrict__ s,
                                                        const int* __restrict__ perm,
                                                        const float* __restrict__ gg,
                                                        const float* __restrict__ bb,
                                                        const float* __restrict__ mm,
                                                        const float* __restrict__ vv,
                                                        float* __restrict__ xp) {
  int j = blockIdx.x, f = threadIdx.x;
  int old = perm[j];
  float t = tanhf(s[old]);
  float val = h[(size_t)old * 128 + f] * t;
  float o = gg[f] * (val - mm[f]) / sqrtf(vv[f] + EPSc) + bb[f];
  xp[(size_t)j * 128 + f] = fmaxf(o, 0.0f);
}

// chunked segment-sum: grid = Bg * nchunk blocks of 128 threads.
// Each block locally accumulates its row chunk, then one atomicAdd per feature.
// (round-1 fix: previous version used 128 blocks total -> 2.7% occupancy, 121 us)
static __global__ __launch_bounds__(128) void k_gsum2(const float* __restrict__ xp,
                                                      float* __restrict__ pooled,
                                                      int nper, int nchunk) {
  int g = blockIdx.x / nchunk, c = blockIdx.x - g * nchunk;
  int f = threadIdx.x;
  int rows = (nper + nchunk - 1) / nchunk;
  int r0 = c * rows;
  int r1 = min(nper, r0 + rows);
  if (r0 >= r1) return;
  float acc = 0.f;
  const float* p = xp + ((size_t)g * nper + r0) * 128 + f;
  for (int i = r0; i < r1; ++i, p += 128) acc += *p;
  atomicAdd(&pooled[g * 128 + f], acc);
}

static __global__ void k_final(const float* __restrict__ pooled,
                               const float* __restrict__ w0, const float* __restrict__ b0,
                               const float* __restrict__ w1, const float* __restrict__ b1,
                               const float* __restrict__ w2, const float* __restrict__ b2,
                               float* __restrict__ out) {
  int t = blockIdx.x * 256 + threadIdx.x;
  if (t >= Bg * DOUTc) return;
  int g = t / DOUTc, o = t - g * DOUTc;
  const float* p0 = pooled + g * 128;
  const float* p1 = pooled + Bg * 128 + g * 128;
  const float* p2 = pooled + 2 * Bg * 128 + g * 128;
  float acc = b0[o] + b1[o] + b2[o];
  for (int k = 0; k < 128; ++k)
    acc += p0[k] * w0[o * 128 + k] + p1[k] * w1[o * 128 + k] + p2[k] * w2[o * 128 + k];
  out[t] = acc;
}

extern "C" void kernel_launch(void* const* d_in, const int* in_sizes, int n_in,
                              void* d_out, int out_size, void* d_ws, size_t ws_size,
                              hipStream_t stream) {
  (void)in_sizes; (void)n_in; (void)out_size; (void)ws_size;
  const float* x    = (const float*)d_in[0];
  const int*   ei   = (const int*)d_in[1];
  const int*   src0 = ei;
  const int*   dst0 = ei + Etot;
  const float* c1W = (const float*)d_in[2];  const float* c1b = (const float*)d_in[3];
  const float* c2W = (const float*)d_in[4];  const float* c2b = (const float*)d_in[5];
  const float* s1W = (const float*)d_in[6];  const float* s1b = (const float*)d_in[7];
  const float* s2W = (const float*)d_in[8];  const float* s2b = (const float*)d_in[9];
  const float* bn1g = (const float*)d_in[10]; const float* bn1b = (const float*)d_in[11];
  const float* bn1m = (const float*)d_in[12]; const float* bn1v = (const float*)d_in[13];
  const float* bn2g = (const float*)d_in[14]; const float* bn2b = (const float*)d_in[15];
  const float* bn2m = (const float*)d_in[16]; const float* bn2v = (const float*)d_in[17];
  const float* l0W = (const float*)d_in[18]; const float* l0b = (const float*)d_in[19];
  const float* l1W = (const float*)d_in[20]; const float* l1b = (const float*)d_in[21];
  const float* l2W = (const float*)d_in[22]; const float* l2b = (const float*)d_in[23];
  float* out = (float*)d_out;

  char* p = (char*)d_ws;
  auto alloc = [&](size_t bytes) { char* q = p; p += (bytes + 255) & ~(size_t)255; return q; };
  float* h0    = (float*)alloc((size_t)N0c * 128 * 4);   // layer1 reuses as g1
  float* h1    = (float*)alloc((size_t)N0c * 128 * 4);   // layer1 reuses as h2
  float* xp1   = (float*)alloc((size_t)N1c * 128 * 4);
  float* xp2   = (float*)alloc((size_t)N2c * 128 * 4);
  int*   cnt   = (int*)alloc((size_t)N0c * 4);
  int*   fcnt  = (int*)alloc((size_t)N0c * 4);
  float* dinv  = (float*)alloc((size_t)N0c * 4);
  int*   rp    = (int*)alloc((size_t)Bg * (NPG + 1) * 4);
  int*   col   = (int*)alloc((size_t)Etot * 4);
  float* cval  = (float*)alloc((size_t)Etot * 4);
  float* spre  = (float*)alloc((size_t)N0c * 4);
  float* sv    = (float*)alloc((size_t)N0c * 4);
  int*   perm  = (int*)alloc((size_t)N1c * 4);
  int*   remap = (int*)alloc((size_t)N0c * 4);
  int*   es    = (int*)alloc((size_t)Etot * 4);
  int*   ed    = (int*)alloc((size_t)Etot * 4);
  float* pooled= (float*)alloc((size_t)3 * Bg * 128 * 4);

  dim3 b256(256), b128(128), b512(512);
  int gE = (Etot + 255) / 256;

  // ---------------- layer 0 ----------------
  k_fill_i32<<<(N0c + 255) / 256, b256, 0, stream>>>(cnt, 0, N0c);
  k_fill_f32<<<(3 * Bg * 128 + 255) / 256, b256, 0, stream>>>(pooled, 0.f, 3 * Bg * 128);
  k_cnt<<<gE, b256, 0, stream>>>(dst0, cnt, Etot);
  k_dinv<<<(N0c + 255) / 256, b256, 0, stream>>>(cnt, dinv, N0c);
  k_rowscan<<<Bg, b512, 0, stream>>>(cnt, rp, NPG);
  k_fill_i32<<<(N0c + 255) / 256, b256, 0, stream>>>(fcnt, 0, N0c);
  k_fill_csr<<<gE, b256, 0, stream>>>(src0, dst0, dinv, rp, fcnt, col, cval, NPG, Etot);
  k_gemm<<<N0c / 64, b256, 0, stream>>>(x, c1W, h0, N0c);
  k_agg<<<N0c, b128, 0, stream>>>(h0, dinv, c1b, rp, col, cval, h1, NPG);
  k_gemv<<<(N0c + 3) / 4, b256, 0, stream>>>(h1, s1W, spre, N0c);
  k_score<<<(N0c + 255) / 256, b256, 0, stream>>>(spre, dinv, s1b, rp, col, cval, sv, NPG, N0c);
  k_topk<NPG, K1c><<<Bg, b256, 0, stream>>>(sv, perm);
  k_fill_i32<<<(N0c + 255) / 256, b256, 0, stream>>>(remap, -1, N0c);
  k_remap_scatter<<<(N1c + 255) / 256, b256, 0, stream>>>(perm, remap, N1c);
  k_edge_remap<<<gE, b256, 0, stream>>>(src0, dst0, remap, es, ed, Etot);
  k_pool_bn<<<N1c, b128, 0, stream>>>(h1, sv, perm, bn1g, bn1b, bn1m, bn1v, xp1);

  // ---------------- layer 1 ----------------
  k_fill_i32<<<(N1c + 255) / 256, b256, 0, stream>>>(cnt, 0, N1c);
  k_cnt<<<gE, b256, 0, stream>>>(ed, cnt, Etot);
  k_dinv<<<(N1c + 255) / 256, b256, 0, stream>>>(cnt, dinv, N1c);
  k_rowscan<<<Bg, b512, 0, stream>>>(cnt, rp, K1c);
  k_fill_i32<<<(N1c + 255) / 256, b256, 0, stream>>>(fcnt, 0, N1c);
  k_fill_csr<<<gE, b256, 0, stream>>>(es, ed, dinv, rp, fcnt, col, cval, K1c, Etot);
  float* g1 = h0;   // h0 dead after layer-0 agg
  float* h2 = h1;   // h1 dead after pool_bn
  k_gemm<<<N1c / 64, b256, 0, stream>>>(xp1, c2W, g1, N1c);
  k_agg<<<N1c, b128, 0, stream>>>(g1, dinv, c2b, rp, col, cval, h2, K1c);
  k_gemv<<<(N1c + 3) / 4, b256, 0, stream>>>(h2, s2W, spre, N1c);
  k_score<<<(N1c + 255) / 256, b256, 0, stream>>>(spre, dinv, s2b, rp, col, cval, sv, K1c, N1c);
  k_topk<K1c, K2c><<<Bg, b256, 0, stream>>>(sv, perm);
  k_pool_bn<<<N2c, b128, 0, stream>>>(h2, sv, perm, bn2g, bn2b, bn2m, bn2v, xp2);

  // ---------------- readout (chunked, atomic combine) ----------------
  k_gsum2<<<Bg * 16, b128, 0, stream>>>(x, pooled, NPG, 16);
  k_gsum2<<<Bg * 16, b128, 0, stream>>>(xp1, pooled + Bg * 128, K1c, 16);
  k_gsum2<<<Bg * 16, b128, 0, stream>>>(xp2, pooled + 2 * Bg * 128, K2c, 16);
  k_final<<<(Bg * DOUTc + 255) / 256, b256, 0, stream>>>(pooled, l0W, l0b, l1W, l1b, l2W, l2b, out);
}